// Round 11
// baseline (499.174 us; speedup 1.0000x reference)
//
#include <hip/hip_runtime.h>
#include <hip/hip_bf16.h>

// ---------------------------------------------------------------------------
// SmallthinkerAttention: hs->QKV proj(+RoPE fused) -> causal attn (writes P) -> out proj
// B=2 S=2048 HID=2048 NH=32 NKV=8 HD=64
// d_out = [out (2*2048*2048 f32), attn_weights (2*32*2048*2048 f32)]
// R11: GEMM reverted to m97 128^2 (R10's 256^2 under-filled the grid: 192/128
//      blocks on 256 CUs). RoPE fused into QKV-GEMM epilogue (wave col-span =
//      one 64-wide head; rotate-half pair = acc frag j / j+2). All casts fused
//      into one kernel. Experiment: P stores NT f32x4 (R7 confounded NT with
//      granularity; fills sustain 6.3+ TB/s, attn only ~4.5 effective).
// ---------------------------------------------------------------------------

typedef __bf16 bf16;
typedef bf16 bf16x8 __attribute__((ext_vector_type(8)));
typedef bf16 bf16x4 __attribute__((ext_vector_type(4)));
typedef float f32x4 __attribute__((ext_vector_type(4)));

#define B_   2
#define S_   2048
#define HID_ 2048
#define NH_  32
#define NKV_ 8
#define HD_  64
#define TOK_ (B_*S_)          // 4096
#define QKVN 3072             // fused QKV output cols: 2048 q | 512 k | 512 v

// barrier WITHOUT the implicit vmcnt(0) drain
#define BAR_LGKM() do { asm volatile("s_waitcnt lgkmcnt(0)" ::: "memory"); \
                        __builtin_amdgcn_s_barrier(); } while (0)

// async global->LDS, 16B per lane, LDS dest = wave-uniform base + lane*16
__device__ __forceinline__ void gl_lds16(const bf16* g, bf16* l) {
  __builtin_amdgcn_global_load_lds(
      (const __attribute__((address_space(1))) unsigned int*)(g),
      (__attribute__((address_space(3))) unsigned int*)(l), 16, 0, 0);
}

// ---------------- fused cast: hs | Wq | Wk | Wv | Wo -> bf16 ----------------
// x4 units: hs 2097152 | Wq 1048576 | Wk 262144 | Wv 262144 | Wo 1048576
__global__ __launch_bounds__(256) void cast_all(const float* __restrict__ hs,
                                                const float* __restrict__ wq,
                                                const float* __restrict__ wk,
                                                const float* __restrict__ wv,
                                                const float* __restrict__ wo,
                                                bf16* __restrict__ hs_b,
                                                bf16* __restrict__ wqkv_b,
                                                bf16* __restrict__ wo_b) {
  int i = blockIdx.x * 256 + threadIdx.x;      // 0 .. 4718591
  const float* src; bf16* dstb; int off;
  if (i < 2097152)      { src = hs; dstb = hs_b;                       off = i; }
  else if (i < 3145728) { src = wq; dstb = wqkv_b;                     off = i - 2097152; }
  else if (i < 3407872) { src = wk; dstb = wqkv_b + (size_t)4194304;   off = i - 3145728; }
  else if (i < 3670016) { src = wv; dstb = wqkv_b + (size_t)5242880;   off = i - 3407872; }
  else                  { src = wo; dstb = wo_b;                       off = i - 3670016; }
  f32x4 v = ((const f32x4*)src)[off];
  bf16x4 o;
  o[0] = (bf16)v[0]; o[1] = (bf16)v[1]; o[2] = (bf16)v[2]; o[3] = (bf16)v[3];
  ((bf16x4*)dstb)[off] = o;
}

// ---------------- GEMM: C[M,N] = A[M,K] @ B[N,K]^T  (m97 128^2 + T1) ----------
// ROPE: wave col-span (wn 64-aligned, 64 wide) = one head; cols < 2560 get
// RoPE in the epilogue: pair (d, d+32) = acc frag j and j+2 (j=0,1).
template<bool OUT_F32, bool ROPE>
__global__ __launch_bounds__(256) void gemm_bt(const bf16* __restrict__ A,
                                               const bf16* __restrict__ Bm,
                                               void* __restrict__ Cout,
                                               int M, int N, int K,
                                               const float* __restrict__ cosp,
                                               const float* __restrict__ sinp) {
  __shared__ __align__(16) bf16 As[128 * 32];
  __shared__ __align__(16) bf16 Bs[128 * 32];
  const int tid  = threadIdx.x;
  const int wave = tid >> 6, lane = tid & 63;

  // T1 XCD-aware swizzle (nwg % 8 == 0 for all our launches)
  const int nwg = (int)(gridDim.x * gridDim.y);
  const int bid = (int)(blockIdx.y * gridDim.x + blockIdx.x);
  const int swz = (bid & 7) * (nwg >> 3) + (bid >> 3);
  const int bx = swz % (int)gridDim.x, by = swz / (int)gridDim.x;

  const int bm = by * 128, bn = bx * 128;
  const int wm = (wave >> 1) * 64, wn = (wave & 1) * 64;
  const int fr = lane & 15, fg = lane >> 4;

  const int r0   = wave * 32 + (lane >> 2);
  const int scol = (lane & 3) * 8;
  const bf16* ga0 = A  + (size_t)(bm + r0) * K + scol;
  const bf16* ga1 = ga0 + (size_t)16 * K;
  const bf16* gb0 = Bm + (size_t)(bn + r0) * K + scol;
  const bf16* gb1 = gb0 + (size_t)16 * K;
  bf16* lA0 = As + (wave * 32) * 32;
  bf16* lA1 = lA0 + 16 * 32;
  bf16* lB0 = Bs + (wave * 32) * 32;
  bf16* lB1 = lB0 + 16 * 32;

  f32x4 acc[4][4] = {};

  for (int k0 = 0; k0 < K; k0 += 32) {
    gl_lds16(ga0 + k0, lA0);
    gl_lds16(ga1 + k0, lA1);
    gl_lds16(gb0 + k0, lB0);
    gl_lds16(gb1 + k0, lB1);
    __syncthreads();
    bf16x8 af[4], bfv[4];
#pragma unroll
    for (int i = 0; i < 4; ++i) {
      af[i]  = *(const bf16x8*)&As[(wm + i * 16 + fr) * 32 + fg * 8];
      bfv[i] = *(const bf16x8*)&Bs[(wn + i * 16 + fr) * 32 + fg * 8];
    }
#pragma unroll
    for (int i = 0; i < 4; ++i)
#pragma unroll
      for (int j = 0; j < 4; ++j)
        acc[i][j] = __builtin_amdgcn_mfma_f32_16x16x32_bf16(af[i], bfv[j], acc[i][j], 0, 0, 0);
    __syncthreads();
  }

  if (ROPE && (bn + wn) < 2560) {
    // roped head (q or k): rotate pairs (d, d+32), d = j*16+fr for j=0,1
    const int hcol = bn + wn;
#pragma unroll
    for (int i = 0; i < 4; ++i)
#pragma unroll
      for (int r = 0; r < 4; ++r) {
        const int row = bm + wm + i * 16 + fg * 4 + r;
        const float* cp = cosp + (size_t)row * 64;
        const float* sp = sinp + (size_t)row * 64;
        bf16* outr = (bf16*)Cout + (size_t)row * N + hcol;
#pragma unroll
        for (int j = 0; j < 2; ++j) {
          const int d = j * 16 + fr;
          const float c = cp[d], s = sp[d];
          const float x1 = acc[i][j][r], x2 = acc[i][j + 2][r];
          outr[d]      = (bf16)(x1 * c - x2 * s);
          outr[d + 32] = (bf16)(x2 * c + x1 * s);
        }
      }
  } else {
#pragma unroll
    for (int i = 0; i < 4; ++i)
#pragma unroll
      for (int j = 0; j < 4; ++j)
#pragma unroll
        for (int r = 0; r < 4; ++r) {
          int row = bm + wm + i * 16 + fg * 4 + r;
          int col = bn + wn + j * 16 + fr;
          float v = acc[i][j][r];
          if (OUT_F32) ((float*)Cout)[(size_t)row * N + col] = v;
          else         ((bf16*)Cout)[(size_t)row * N + col] = (bf16)v;
        }
  }
}

// ---------------- transpose V: qkv v-cols -> vT[(b*8+kv)][64][2048] ----------
__global__ __launch_bounds__(256) void transpose_v(const bf16* __restrict__ v,  // qkv + 2560
                                                   bf16* __restrict__ vT) {
  __shared__ __align__(16) bf16 t[64][72];
  const int bkv = blockIdx.y;
  const int b = bkv >> 3, kv = bkv & 7;
  const int s0 = blockIdx.x * 64;
  const int tid = threadIdx.x;
  const int r = tid >> 3, c = (tid & 7) * 8;
#pragma unroll
  for (int p = 0; p < 2; ++p) {
    int rr = r + p * 32;
    *(bf16x8*)&t[rr][c] = *(const bf16x8*)&v[(size_t)(b * S_ + s0 + rr) * QKVN + kv * 64 + c];
  }
  __syncthreads();
#pragma unroll
  for (int p = 0; p < 2; ++p) {
    int d = r + p * 32;
    bf16x8 o;
#pragma unroll
    for (int j = 0; j < 8; ++j) o[j] = t[c + j][d];
    *(bf16x8*)&vT[((size_t)bkv * 64 + d) * S_ + s0 + c] = o;
  }
}

// ---------------- fused causal attention (stripe-paired, 4 waves) ----------------
// R9 structure; experiment: P stores are now NT f32x4 (write-once stream,
// bypass L2 allocation). Zero-fill NT as before.
__global__ __launch_bounds__(256, 4) void attn_kernel(const bf16* __restrict__ qkv, // (TOK, 3072)
                                                      const bf16* __restrict__ vT,  // (16,64,2048)
                                                      float* __restrict__ attnw,    // (64, S, S)
                                                      bf16* __restrict__ attn_out)  // (TOK, 2048)
{
  __shared__ __align__(16) bf16 Ks2[2][64][72];
  __shared__ __align__(16) bf16 Vs[64][72];
  __shared__ __align__(16) bf16 Ps[4][16][72];

  const int tid  = threadIdx.x;
  const int wave = tid >> 6, lane = tid & 63;
  const int qt = blockIdx.x;                   // 0..15
  const int bh = blockIdx.y;                   // 0..63
  const int b = bh >> 5, h = bh & 31, kv = h >> 2;
  const int qLo = qt * 64;                     // LO stripe base row
  const int qHi = (31 - qt) * 64;              // HI stripe base row
  const int NT  = 32 - qt;                     // K/V tiles staged (HI needs all)
  const int fr = lane & 15, fg = lane >> 4;
  const int rw = wave * 16;                    // wave's row base within stripe
  const int rt = rw + fg * 4;                  // attn_out row group
  const int thr = rw + fr;                     // lane's q-row within stripe (diag threshold)

  const int lr = tid >> 2;                     // 0..63
  const int lc = (tid & 3) * 16;               // 0,16,32,48
  const bf16* kbase = qkv + (size_t)(b * S_) * QKVN + 2048 + kv * 64;
  const bf16* vbase = vT + (size_t)(b * NKV_ + kv) * 64 * S_;
  const bf16* kst = kbase + (size_t)lr * QKVN + lc;   // + jt*64*QKVN
  const bf16* vst = vbase + (size_t)lr * S_ + lc;     // + jt*64

  // tile-0 K loads FIRST (in-order vmcnt: retire before the zero-fill stores)
  bf16x8 kr0 = *(const bf16x8*)(kst);
  bf16x8 kr1 = *(const bf16x8*)(kst + 8);

  // Q fragments for both stripes (K=64 -> 2 chunks of 32); used as MFMA B-operand.
  bf16x8 aqL[2], aqH[2];
  {
    const bf16* qp = qkv + (size_t)(b * S_ + qLo + rw + fr) * QKVN + h * 64 + fg * 8;
    aqL[0] = *(const bf16x8*)qp;  aqL[1] = *(const bf16x8*)(qp + 32);
    qp = qkv + (size_t)(b * S_ + qHi + rw + fr) * QKVN + h * 64 + fg * 8;
    aqH[0] = *(const bf16x8*)qp;  aqH[1] = *(const bf16x8*)(qp + 32);
  }

  // ---------- zero-fill masked regions (background NT stores) ----------
  {
    f32x4 z4 = {0.f, 0.f, 0.f, 0.f};
    const int zLo = (qt + 1) * 64;              // LO rows: cols [zLo, S)
    for (int rr = 0; rr < 16; ++rr) {
      size_t base = ((size_t)bh * S_ + qLo + rw + rr) * S_;
      for (int c = zLo + lane * 4; c < S_; c += 256)
        __builtin_nontemporal_store(z4, (f32x4*)&attnw[base + c]);
    }
    const int zHi = NT * 64;                    // HI rows: cols [zHi, S)
    for (int rr = 0; rr < 16; ++rr) {
      size_t base = ((size_t)bh * S_ + qHi + rw + rr) * S_;
      for (int c = zHi + lane * 4; c < S_; c += 256)
        __builtin_nontemporal_store(z4, (f32x4*)&attnw[base + c]);
    }
  }

  // ---------- pass 1: rowsums of exp(logit), K double-buffered ----------
  float rsL = 0.f, rsH = 0.f;                  // scalar: lane owns q-row fr
  {
    *(bf16x8*)&Ks2[0][lr][lc]     = kr0;
    *(bf16x8*)&Ks2[0][lr][lc + 8] = kr1;
    BAR_LGKM();
    for (int jt = 0; jt < NT; ++jt) {
      const int cur = jt & 1;
      if (jt + 1 < NT) {                        // prefetch next tile to regs
        const bf16* p = kst + (size_t)(jt + 1) * 64 * QKVN;
        kr0 = *(const bf16x8*)(p);
        kr1 = *(const bf16x8*)(p + 8);
      }
      // HI stripe (always active)
      {
        f32x4 acc[4] = {};
#pragma unroll
        for (int nn = 0; nn < 4; ++nn) {
          bf16x8 bk0 = *(const bf16x8*)&Ks2[cur][nn*16 + fr][fg*8];
          bf16x8 bk1 = *(const bf16x8*)&Ks2[cur][nn*16 + fr][32 + fg*8];
          acc[nn] = __builtin_amdgcn_mfma_f32_16x16x32_bf16(bk0, aqH[0], acc[nn], 0, 0, 0);
          acc[nn] = __builtin_amdgcn_mfma_f32_16x16x32_bf16(bk1, aqH[1], acc[nn], 0, 0, 0);
        }
        if (jt < NT - 1) {                      // fully unmasked
#pragma unroll
          for (int nn = 0; nn < 4; ++nn)
#pragma unroll
            for (int r = 0; r < 4; ++r) rsH += __expf(acc[nn][r] * 0.125f);
        } else {                                // HI diagonal tile: k <= q
#pragma unroll
          for (int nn = 0; nn < 4; ++nn)
#pragma unroll
            for (int r = 0; r < 4; ++r)
              if (nn * 16 + fg * 4 + r <= thr) rsH += __expf(acc[nn][r] * 0.125f);
        }
      }
      // LO stripe (active for jt <= qt; block-uniform)
      if (jt <= qt) {
        f32x4 acc[4] = {};
#pragma unroll
        for (int nn = 0; nn < 4; ++nn) {
          bf16x8 bk0 = *(const bf16x8*)&Ks2[cur][nn*16 + fr][fg*8];
          bf16x8 bk1 = *(const bf16x8*)&Ks2[cur][nn*16 + fr][32 + fg*8];
          acc[nn] = __builtin_amdgcn_mfma_f32_16x16x32_bf16(bk0, aqL[0], acc[nn], 0, 0, 0);
          acc[nn] = __builtin_amdgcn_mfma_f32_16x16x32_bf16(bk1, aqL[1], acc[nn], 0, 0, 0);
        }
        if (jt < qt) {
#pragma unroll
          for (int nn = 0; nn < 4; ++nn)
#pragma unroll
            for (int r = 0; r < 4; ++r) rsL += __expf(acc[nn][r] * 0.125f);
        } else {                                // LO diagonal tile
#pragma unroll
          for (int nn = 0; nn < 4; ++nn)
#pragma unroll
            for (int r = 0; r < 4; ++r)
              if (nn * 16 + fg * 4 + r <= thr) rsL += __expf(acc[nn][r] * 0.125f);
        }
      }
      if (jt + 1 < NT) {                        // stage next tile, ONE barrier
        *(bf16x8*)&Ks2[cur ^ 1][lr][lc]     = kr0;
        *(bf16x8*)&Ks2[cur ^ 1][lr][lc + 8] = kr1;
        BAR_LGKM();
      }
    }
  }
  // reduce across the 4 fg lane-groups (k-partitions), then invert
  {
    float v = rsL;
    v += __shfl_xor(v, 16); v += __shfl_xor(v, 32);
    rsL = 1.0f / v;
    v = rsH;
    v += __shfl_xor(v, 16); v += __shfl_xor(v, 32);
    rsH = 1.0f / v;
  }

  // ---------- pass 2: recompute (swapped), write P NT f32x4, accumulate O ----------
  f32x4 oL[4] = {}, oH[4] = {};
  {
    float* awpL = attnw + ((size_t)bh * S_ + qLo + rw + fr) * S_;   // lane's LO row
    float* awpH = attnw + ((size_t)bh * S_ + qHi + rw + fr) * S_;   // lane's HI row
    const int cb = fg * 4;                      // lane's 4-col base within 16-window
    kr0 = *(const bf16x8*)(kst);               // prefetch tile 0
    kr1 = *(const bf16x8*)(kst + 8);
    bf16x8 vr0 = *(const bf16x8*)(vst);
    bf16x8 vr1 = *(const bf16x8*)(vst + 8);
    for (int jt = 0; jt < NT; ++jt) {
      const int j0 = jt * 64;
      BAR_LGKM();                               // all waves done reading prev tile
      *(bf16x8*)&Ks2[0][lr][lc]     = kr0;
      *(bf16x8*)&Ks2[0][lr][lc + 8] = kr1;
      *(bf16x8*)&Vs[lr][lc]     = vr0;
      *(bf16x8*)&Vs[lr][lc + 8] = vr1;
      BAR_LGKM();                               // stage visible
      if (jt + 1 < NT) {                        // loads issued BEFORE this tile's stores
        const bf16* p = kst + (size_t)(jt + 1) * 64 * QKVN;
        kr0 = *(const bf16x8*)(p);
        kr1 = *(const bf16x8*)(p + 8);
        p = vst + (size_t)(jt + 1) * 64;
        vr0 = *(const bf16x8*)(p);
        vr1 = *(const bf16x8*)(p + 8);
      }
      // ---- HI stripe (always) ----
      {
        f32x4 acc[4] = {};
#pragma unroll
        for (int nn = 0; nn < 4; ++nn) {
          bf16x8 bk0 = *(const bf16x8*)&Ks2[0][nn*16 + fr][fg*8];
          bf16x8 bk1 = *(const bf16x8*)&Ks2[0][nn*16 + fr][32 + fg*8];
          acc[nn] = __builtin_amdgcn_mfma_f32_16x16x32_bf16(bk0, aqH[0], acc[nn], 0, 0, 0);
          acc[nn] = __builtin_amdgcn_mfma_f32_16x16x32_bf16(bk1, aqH[1], acc[nn], 0, 0, 0);
        }
        const bool diag = (jt == NT - 1);
#pragma unroll
        for (int nn = 0; nn < 4; ++nn) {
          f32x4 pv;
          bf16x4 pb;
#pragma unroll
          for (int r = 0; r < 4; ++r) {
            float e = __expf(acc[nn][r] * 0.125f) * rsH;
            pv[r] = (diag && (nn * 16 + cb + r > thr)) ? 0.f : e;
            pb[r] = (bf16)pv[r];
          }
          __builtin_nontemporal_store(pv, (f32x4*)&awpH[j0 + nn * 16 + cb]);
          *(bf16x4*)&Ps[wave][fr][nn * 16 + cb] = pb;
        }
        bf16x8 pa0 = *(const bf16x8*)&Ps[wave][fr][fg * 8];
        bf16x8 pa1 = *(const bf16x8*)&Ps[wave][fr][32 + fg * 8];
#pragma unroll
        for (int nn = 0; nn < 4; ++nn) {
          bf16x8 bv0 = *(const bf16x8*)&Vs[nn*16 + fr][fg*8];
          bf16x8 bv1 = *(const bf16x8*)&Vs[nn*16 + fr][32 + fg*8];
          oH[nn] = __builtin_amdgcn_mfma_f32_16x16x32_bf16(pa0, bv0, oH[nn], 0, 0, 0);
          oH[nn] = __builtin_amdgcn_mfma_f32_16x16x32_bf16(pa1, bv1, oH[nn], 0, 0, 0);
        }
      }
      // ---- LO stripe (jt <= qt; block-uniform) ----
      if (jt <= qt) {
        f32x4 acc[4] = {};
#pragma unroll
        for (int nn = 0; nn < 4; ++nn) {
          bf16x8 bk0 = *(const bf16x8*)&Ks2[0][nn*16 + fr][fg*8];
          bf16x8 bk1 = *(const bf16x8*)&Ks2[0][nn*16 + fr][32 + fg*8];
          acc[nn] = __builtin_amdgcn_mfma_f32_16x16x32_bf16(bk0, aqL[0], acc[nn], 0, 0, 0);
          acc[nn] = __builtin_amdgcn_mfma_f32_16x16x32_bf16(bk1, aqL[1], acc[nn], 0, 0, 0);
        }
        const bool diag = (jt == qt);
#pragma unroll
        for (int nn = 0; nn < 4; ++nn) {
          f32x4 pv;
          bf16x4 pb;
#pragma unroll
          for (int r = 0; r < 4; ++r) {
            float e = __expf(acc[nn][r] * 0.125f) * rsL;
            pv[r] = (diag && (nn * 16 + cb + r > thr)) ? 0.f : e;
            pb[r] = (bf16)pv[r];
          }
          __builtin_nontemporal_store(pv, (f32x4*)&awpL[j0 + nn * 16 + cb]);
          *(bf16x4*)&Ps[wave][fr][nn * 16 + cb] = pb;
        }
        bf16x8 pa0 = *(const bf16x8*)&Ps[wave][fr][fg * 8];
        bf16x8 pa1 = *(const bf16x8*)&Ps[wave][fr][32 + fg * 8];
#pragma unroll
        for (int nn = 0; nn < 4; ++nn) {
          bf16x8 bv0 = *(const bf16x8*)&Vs[nn*16 + fr][fg*8];
          bf16x8 bv1 = *(const bf16x8*)&Vs[nn*16 + fr][32 + fg*8];
          oL[nn] = __builtin_amdgcn_mfma_f32_16x16x32_bf16(pa0, bv0, oL[nn], 0, 0, 0);
          oL[nn] = __builtin_amdgcn_mfma_f32_16x16x32_bf16(pa1, bv1, oL[nn], 0, 0, 0);
        }
      }
    }
  }

  // attn_out (bf16) for both stripes (PV D-layout: row q = rt+r, col d = nn*16+fr)
#pragma unroll
  for (int nn = 0; nn < 4; ++nn)
#pragma unroll
    for (int r = 0; r < 4; ++r) {
      int rowL = qLo + rt + r;
      int rowH = qHi + rt + r;
      attn_out[(size_t)(b * S_ + rowL) * (NH_*HD_) + h * 64 + nn * 16 + fr] = (bf16)oL[nn][r];
      attn_out[(size_t)(b * S_ + rowH) * (NH_*HD_) + h * 64 + nn * 16 + fr] = (bf16)oH[nn][r];
    }
}

// ---------------------------------------------------------------------------
extern "C" void kernel_launch(void* const* d_in, const int* in_sizes, int n_in,
                              void* d_out, int out_size, void* d_ws, size_t ws_size,
                              hipStream_t stream) {
  const float* hs   = (const float*)d_in[0];
  const float* cosp = (const float*)d_in[1];
  const float* sinp = (const float*)d_in[2];
  // d_in[3] = attention_mask (causal; applied analytically)
  const float* Wq = (const float*)d_in[4];
  const float* Wk = (const float*)d_in[5];
  const float* Wv = (const float*)d_in[6];
  const float* Wo = (const float*)d_in[7];

  char* ws = (char*)d_ws;
  bf16* hs_b   = (bf16*)(ws);                   // 16 MB
  bf16* qkv_b  = (bf16*)(ws + (16u << 20));     // 24 MB (TOK x 3072)
  bf16* vT_b   = (bf16*)(ws + (40u << 20));     // 4 MB
  bf16* ao_b   = (bf16*)(ws + (44u << 20));     // 16 MB
  bf16* Wqkv_b = (bf16*)(ws + (60u << 20));     // 12 MB (3072 x 2048)
  bf16* Wo_b   = (bf16*)(ws + (72u << 20));     // 8 MB

  float* outp  = (float*)d_out;
  float* attnw = outp + (size_t)TOK_ * HID_;    // + 8388608

  // all casts in one kernel
  cast_all<<<(4718592 + 255)/256, 256, 0, stream>>>(hs, Wq, Wk, Wv, Wo,
                                                    hs_b, Wqkv_b, Wo_b);

  // fused QKV projection + RoPE epilogue: (TOK,2048) @ (3072,2048)^T -> (TOK,3072)
  gemm_bt<false, true><<<dim3(QKVN/128, TOK_/128), 256, 0, stream>>>(
      hs_b, Wqkv_b, qkv_b, TOK_, QKVN, HID_, cosp, sinp);

  // V transpose for PV B-operand contiguity
  transpose_v<<<dim3(S_/64, B_*NKV_), 256, 0, stream>>>(qkv_b + 2560, vT_b);

  // fused attention (stripe-paired; writes attn_weights f32 + attn_out bf16)
  attn_kernel<<<dim3(S_/128, B_*NH_), 256, 0, stream>>>(qkv_b, vT_b, attnw, ao_b);

  // output projection (f32 out)
  gemm_bt<true, false><<<dim3(HID_/128, TOK_/128), 256, 0, stream>>>(
      ao_b, Wo_b, outp, TOK_, HID_, HID_, nullptr, nullptr);
}

// Round 12
// 449.689 us; speedup vs baseline: 1.1100x; 1.1100x over previous
//
#include <hip/hip_runtime.h>
#include <hip/hip_bf16.h>

// ---------------------------------------------------------------------------
// SmallthinkerAttention: hs->QKV proj(+RoPE fused) -> causal attn (writes P) -> out proj
// B=2 S=2048 HID=2048 NH=32 NKV=8 HD=64
// d_out = [out (2*2048*2048 f32), attn_weights (2*32*2048*2048 f32)]
// R12: single-variable fix of R11 — P-tile stores back to CACHED f32x4 (NT on
//      the 16-row-scattered P pattern caused partial-line HBM writes, −66us).
//      NT kept only on the contiguous zero-fill. cast_all + RoPE-fused QKV GEMM
//      retained from R11.
// ---------------------------------------------------------------------------

typedef __bf16 bf16;
typedef bf16 bf16x8 __attribute__((ext_vector_type(8)));
typedef bf16 bf16x4 __attribute__((ext_vector_type(4)));
typedef float f32x4 __attribute__((ext_vector_type(4)));

#define B_   2
#define S_   2048
#define HID_ 2048
#define NH_  32
#define NKV_ 8
#define HD_  64
#define TOK_ (B_*S_)          // 4096
#define QKVN 3072             // fused QKV output cols: 2048 q | 512 k | 512 v

// barrier WITHOUT the implicit vmcnt(0) drain
#define BAR_LGKM() do { asm volatile("s_waitcnt lgkmcnt(0)" ::: "memory"); \
                        __builtin_amdgcn_s_barrier(); } while (0)

// async global->LDS, 16B per lane, LDS dest = wave-uniform base + lane*16
__device__ __forceinline__ void gl_lds16(const bf16* g, bf16* l) {
  __builtin_amdgcn_global_load_lds(
      (const __attribute__((address_space(1))) unsigned int*)(g),
      (__attribute__((address_space(3))) unsigned int*)(l), 16, 0, 0);
}

// ---------------- fused cast: hs | Wq | Wk | Wv | Wo -> bf16 ----------------
// x4 units: hs 2097152 | Wq 1048576 | Wk 262144 | Wv 262144 | Wo 1048576
__global__ __launch_bounds__(256) void cast_all(const float* __restrict__ hs,
                                                const float* __restrict__ wq,
                                                const float* __restrict__ wk,
                                                const float* __restrict__ wv,
                                                const float* __restrict__ wo,
                                                bf16* __restrict__ hs_b,
                                                bf16* __restrict__ wqkv_b,
                                                bf16* __restrict__ wo_b) {
  int i = blockIdx.x * 256 + threadIdx.x;      // 0 .. 4718591
  const float* src; bf16* dstb; int off;
  if (i < 2097152)      { src = hs; dstb = hs_b;                       off = i; }
  else if (i < 3145728) { src = wq; dstb = wqkv_b;                     off = i - 2097152; }
  else if (i < 3407872) { src = wk; dstb = wqkv_b + (size_t)4194304;   off = i - 3145728; }
  else if (i < 3670016) { src = wv; dstb = wqkv_b + (size_t)5242880;   off = i - 3407872; }
  else                  { src = wo; dstb = wo_b;                       off = i - 3670016; }
  f32x4 v = ((const f32x4*)src)[off];
  bf16x4 o;
  o[0] = (bf16)v[0]; o[1] = (bf16)v[1]; o[2] = (bf16)v[2]; o[3] = (bf16)v[3];
  ((bf16x4*)dstb)[off] = o;
}

// ---------------- GEMM: C[M,N] = A[M,K] @ B[N,K]^T  (m97 128^2 + T1) ----------
// ROPE: wave col-span (wn 64-aligned, 64 wide) = one head; cols < 2560 get
// RoPE in the epilogue: pair (d, d+32) = acc frag j and j+2 (j=0,1).
template<bool OUT_F32, bool ROPE>
__global__ __launch_bounds__(256) void gemm_bt(const bf16* __restrict__ A,
                                               const bf16* __restrict__ Bm,
                                               void* __restrict__ Cout,
                                               int M, int N, int K,
                                               const float* __restrict__ cosp,
                                               const float* __restrict__ sinp) {
  __shared__ __align__(16) bf16 As[128 * 32];
  __shared__ __align__(16) bf16 Bs[128 * 32];
  const int tid  = threadIdx.x;
  const int wave = tid >> 6, lane = tid & 63;

  // T1 XCD-aware swizzle (nwg % 8 == 0 for all our launches)
  const int nwg = (int)(gridDim.x * gridDim.y);
  const int bid = (int)(blockIdx.y * gridDim.x + blockIdx.x);
  const int swz = (bid & 7) * (nwg >> 3) + (bid >> 3);
  const int bx = swz % (int)gridDim.x, by = swz / (int)gridDim.x;

  const int bm = by * 128, bn = bx * 128;
  const int wm = (wave >> 1) * 64, wn = (wave & 1) * 64;
  const int fr = lane & 15, fg = lane >> 4;

  const int r0   = wave * 32 + (lane >> 2);
  const int scol = (lane & 3) * 8;
  const bf16* ga0 = A  + (size_t)(bm + r0) * K + scol;
  const bf16* ga1 = ga0 + (size_t)16 * K;
  const bf16* gb0 = Bm + (size_t)(bn + r0) * K + scol;
  const bf16* gb1 = gb0 + (size_t)16 * K;
  bf16* lA0 = As + (wave * 32) * 32;
  bf16* lA1 = lA0 + 16 * 32;
  bf16* lB0 = Bs + (wave * 32) * 32;
  bf16* lB1 = lB0 + 16 * 32;

  f32x4 acc[4][4] = {};

  for (int k0 = 0; k0 < K; k0 += 32) {
    gl_lds16(ga0 + k0, lA0);
    gl_lds16(ga1 + k0, lA1);
    gl_lds16(gb0 + k0, lB0);
    gl_lds16(gb1 + k0, lB1);
    __syncthreads();
    bf16x8 af[4], bfv[4];
#pragma unroll
    for (int i = 0; i < 4; ++i) {
      af[i]  = *(const bf16x8*)&As[(wm + i * 16 + fr) * 32 + fg * 8];
      bfv[i] = *(const bf16x8*)&Bs[(wn + i * 16 + fr) * 32 + fg * 8];
    }
#pragma unroll
    for (int i = 0; i < 4; ++i)
#pragma unroll
      for (int j = 0; j < 4; ++j)
        acc[i][j] = __builtin_amdgcn_mfma_f32_16x16x32_bf16(af[i], bfv[j], acc[i][j], 0, 0, 0);
    __syncthreads();
  }

  if (ROPE && (bn + wn) < 2560) {
    // roped head (q or k): rotate pairs (d, d+32), d = j*16+fr for j=0,1
    const int hcol = bn + wn;
#pragma unroll
    for (int i = 0; i < 4; ++i)
#pragma unroll
      for (int r = 0; r < 4; ++r) {
        const int row = bm + wm + i * 16 + fg * 4 + r;
        const float* cp = cosp + (size_t)row * 64;
        const float* sp = sinp + (size_t)row * 64;
        bf16* outr = (bf16*)Cout + (size_t)row * N + hcol;
#pragma unroll
        for (int j = 0; j < 2; ++j) {
          const int d = j * 16 + fr;
          const float c = cp[d], s = sp[d];
          const float x1 = acc[i][j][r], x2 = acc[i][j + 2][r];
          outr[d]      = (bf16)(x1 * c - x2 * s);
          outr[d + 32] = (bf16)(x2 * c + x1 * s);
        }
      }
  } else {
#pragma unroll
    for (int i = 0; i < 4; ++i)
#pragma unroll
      for (int j = 0; j < 4; ++j)
#pragma unroll
        for (int r = 0; r < 4; ++r) {
          int row = bm + wm + i * 16 + fg * 4 + r;
          int col = bn + wn + j * 16 + fr;
          float v = acc[i][j][r];
          if (OUT_F32) ((float*)Cout)[(size_t)row * N + col] = v;
          else         ((bf16*)Cout)[(size_t)row * N + col] = (bf16)v;
        }
  }
}

// ---------------- transpose V: qkv v-cols -> vT[(b*8+kv)][64][2048] ----------
__global__ __launch_bounds__(256) void transpose_v(const bf16* __restrict__ v,  // qkv + 2560
                                                   bf16* __restrict__ vT) {
  __shared__ __align__(16) bf16 t[64][72];
  const int bkv = blockIdx.y;
  const int b = bkv >> 3, kv = bkv & 7;
  const int s0 = blockIdx.x * 64;
  const int tid = threadIdx.x;
  const int r = tid >> 3, c = (tid & 7) * 8;
#pragma unroll
  for (int p = 0; p < 2; ++p) {
    int rr = r + p * 32;
    *(bf16x8*)&t[rr][c] = *(const bf16x8*)&v[(size_t)(b * S_ + s0 + rr) * QKVN + kv * 64 + c];
  }
  __syncthreads();
#pragma unroll
  for (int p = 0; p < 2; ++p) {
    int d = r + p * 32;
    bf16x8 o;
#pragma unroll
    for (int j = 0; j < 8; ++j) o[j] = t[c + j][d];
    *(bf16x8*)&vT[((size_t)bkv * 64 + d) * S_ + s0 + c] = o;
  }
}

// ---------------- fused causal attention (stripe-paired, 4 waves) ----------------
// R9 structure: swapped QK^T, raw lgkm barriers, zero-fill first (NT),
// pass1 K-dbuf, pass2 cached f32x4 P stores + PV accumulate.
__global__ __launch_bounds__(256, 4) void attn_kernel(const bf16* __restrict__ qkv, // (TOK, 3072)
                                                      const bf16* __restrict__ vT,  // (16,64,2048)
                                                      float* __restrict__ attnw,    // (64, S, S)
                                                      bf16* __restrict__ attn_out)  // (TOK, 2048)
{
  __shared__ __align__(16) bf16 Ks2[2][64][72];
  __shared__ __align__(16) bf16 Vs[64][72];
  __shared__ __align__(16) bf16 Ps[4][16][72];

  const int tid  = threadIdx.x;
  const int wave = tid >> 6, lane = tid & 63;
  const int qt = blockIdx.x;                   // 0..15
  const int bh = blockIdx.y;                   // 0..63
  const int b = bh >> 5, h = bh & 31, kv = h >> 2;
  const int qLo = qt * 64;                     // LO stripe base row
  const int qHi = (31 - qt) * 64;              // HI stripe base row
  const int NT  = 32 - qt;                     // K/V tiles staged (HI needs all)
  const int fr = lane & 15, fg = lane >> 4;
  const int rw = wave * 16;                    // wave's row base within stripe
  const int rt = rw + fg * 4;                  // attn_out row group
  const int thr = rw + fr;                     // lane's q-row within stripe (diag threshold)

  const int lr = tid >> 2;                     // 0..63
  const int lc = (tid & 3) * 16;               // 0,16,32,48
  const bf16* kbase = qkv + (size_t)(b * S_) * QKVN + 2048 + kv * 64;
  const bf16* vbase = vT + (size_t)(b * NKV_ + kv) * 64 * S_;
  const bf16* kst = kbase + (size_t)lr * QKVN + lc;   // + jt*64*QKVN
  const bf16* vst = vbase + (size_t)lr * S_ + lc;     // + jt*64

  // tile-0 K loads FIRST (in-order vmcnt: retire before the zero-fill stores)
  bf16x8 kr0 = *(const bf16x8*)(kst);
  bf16x8 kr1 = *(const bf16x8*)(kst + 8);

  // Q fragments for both stripes (K=64 -> 2 chunks of 32); used as MFMA B-operand.
  bf16x8 aqL[2], aqH[2];
  {
    const bf16* qp = qkv + (size_t)(b * S_ + qLo + rw + fr) * QKVN + h * 64 + fg * 8;
    aqL[0] = *(const bf16x8*)qp;  aqL[1] = *(const bf16x8*)(qp + 32);
    qp = qkv + (size_t)(b * S_ + qHi + rw + fr) * QKVN + h * 64 + fg * 8;
    aqH[0] = *(const bf16x8*)qp;  aqH[1] = *(const bf16x8*)(qp + 32);
  }

  // ---------- zero-fill masked regions (background NT stores) ----------
  {
    f32x4 z4 = {0.f, 0.f, 0.f, 0.f};
    const int zLo = (qt + 1) * 64;              // LO rows: cols [zLo, S)
    for (int rr = 0; rr < 16; ++rr) {
      size_t base = ((size_t)bh * S_ + qLo + rw + rr) * S_;
      for (int c = zLo + lane * 4; c < S_; c += 256)
        __builtin_nontemporal_store(z4, (f32x4*)&attnw[base + c]);
    }
    const int zHi = NT * 64;                    // HI rows: cols [zHi, S)
    for (int rr = 0; rr < 16; ++rr) {
      size_t base = ((size_t)bh * S_ + qHi + rw + rr) * S_;
      for (int c = zHi + lane * 4; c < S_; c += 256)
        __builtin_nontemporal_store(z4, (f32x4*)&attnw[base + c]);
    }
  }

  // ---------- pass 1: rowsums of exp(logit), K double-buffered ----------
  float rsL = 0.f, rsH = 0.f;                  // scalar: lane owns q-row fr
  {
    *(bf16x8*)&Ks2[0][lr][lc]     = kr0;
    *(bf16x8*)&Ks2[0][lr][lc + 8] = kr1;
    BAR_LGKM();
    for (int jt = 0; jt < NT; ++jt) {
      const int cur = jt & 1;
      if (jt + 1 < NT) {                        // prefetch next tile to regs
        const bf16* p = kst + (size_t)(jt + 1) * 64 * QKVN;
        kr0 = *(const bf16x8*)(p);
        kr1 = *(const bf16x8*)(p + 8);
      }
      // HI stripe (always active)
      {
        f32x4 acc[4] = {};
#pragma unroll
        for (int nn = 0; nn < 4; ++nn) {
          bf16x8 bk0 = *(const bf16x8*)&Ks2[cur][nn*16 + fr][fg*8];
          bf16x8 bk1 = *(const bf16x8*)&Ks2[cur][nn*16 + fr][32 + fg*8];
          acc[nn] = __builtin_amdgcn_mfma_f32_16x16x32_bf16(bk0, aqH[0], acc[nn], 0, 0, 0);
          acc[nn] = __builtin_amdgcn_mfma_f32_16x16x32_bf16(bk1, aqH[1], acc[nn], 0, 0, 0);
        }
        if (jt < NT - 1) {                      // fully unmasked
#pragma unroll
          for (int nn = 0; nn < 4; ++nn)
#pragma unroll
            for (int r = 0; r < 4; ++r) rsH += __expf(acc[nn][r] * 0.125f);
        } else {                                // HI diagonal tile: k <= q
#pragma unroll
          for (int nn = 0; nn < 4; ++nn)
#pragma unroll
            for (int r = 0; r < 4; ++r)
              if (nn * 16 + fg * 4 + r <= thr) rsH += __expf(acc[nn][r] * 0.125f);
        }
      }
      // LO stripe (active for jt <= qt; block-uniform)
      if (jt <= qt) {
        f32x4 acc[4] = {};
#pragma unroll
        for (int nn = 0; nn < 4; ++nn) {
          bf16x8 bk0 = *(const bf16x8*)&Ks2[cur][nn*16 + fr][fg*8];
          bf16x8 bk1 = *(const bf16x8*)&Ks2[cur][nn*16 + fr][32 + fg*8];
          acc[nn] = __builtin_amdgcn_mfma_f32_16x16x32_bf16(bk0, aqL[0], acc[nn], 0, 0, 0);
          acc[nn] = __builtin_amdgcn_mfma_f32_16x16x32_bf16(bk1, aqL[1], acc[nn], 0, 0, 0);
        }
        if (jt < qt) {
#pragma unroll
          for (int nn = 0; nn < 4; ++nn)
#pragma unroll
            for (int r = 0; r < 4; ++r) rsL += __expf(acc[nn][r] * 0.125f);
        } else {                                // LO diagonal tile
#pragma unroll
          for (int nn = 0; nn < 4; ++nn)
#pragma unroll
            for (int r = 0; r < 4; ++r)
              if (nn * 16 + fg * 4 + r <= thr) rsL += __expf(acc[nn][r] * 0.125f);
        }
      }
      if (jt + 1 < NT) {                        // stage next tile, ONE barrier
        *(bf16x8*)&Ks2[cur ^ 1][lr][lc]     = kr0;
        *(bf16x8*)&Ks2[cur ^ 1][lr][lc + 8] = kr1;
        BAR_LGKM();
      }
    }
  }
  // reduce across the 4 fg lane-groups (k-partitions), then invert
  {
    float v = rsL;
    v += __shfl_xor(v, 16); v += __shfl_xor(v, 32);
    rsL = 1.0f / v;
    v = rsH;
    v += __shfl_xor(v, 16); v += __shfl_xor(v, 32);
    rsH = 1.0f / v;
  }

  // ---------- pass 2: recompute (swapped), write P cached f32x4, accumulate O ----------
  f32x4 oL[4] = {}, oH[4] = {};
  {
    float* awpL = attnw + ((size_t)bh * S_ + qLo + rw + fr) * S_;   // lane's LO row
    float* awpH = attnw + ((size_t)bh * S_ + qHi + rw + fr) * S_;   // lane's HI row
    const int cb = fg * 4;                      // lane's 4-col base within 16-window
    kr0 = *(const bf16x8*)(kst);               // prefetch tile 0
    kr1 = *(const bf16x8*)(kst + 8);
    bf16x8 vr0 = *(const bf16x8*)(vst);
    bf16x8 vr1 = *(const bf16x8*)(vst + 8);
    for (int jt = 0; jt < NT; ++jt) {
      const int j0 = jt * 64;
      BAR_LGKM();                               // all waves done reading prev tile
      *(bf16x8*)&Ks2[0][lr][lc]     = kr0;
      *(bf16x8*)&Ks2[0][lr][lc + 8] = kr1;
      *(bf16x8*)&Vs[lr][lc]     = vr0;
      *(bf16x8*)&Vs[lr][lc + 8] = vr1;
      BAR_LGKM();                               // stage visible
      if (jt + 1 < NT) {                        // loads issued BEFORE this tile's stores
        const bf16* p = kst + (size_t)(jt + 1) * 64 * QKVN;
        kr0 = *(const bf16x8*)(p);
        kr1 = *(const bf16x8*)(p + 8);
        p = vst + (size_t)(jt + 1) * 64;
        vr0 = *(const bf16x8*)(p);
        vr1 = *(const bf16x8*)(p + 8);
      }
      // ---- HI stripe (always) ----
      {
        f32x4 acc[4] = {};
#pragma unroll
        for (int nn = 0; nn < 4; ++nn) {
          bf16x8 bk0 = *(const bf16x8*)&Ks2[0][nn*16 + fr][fg*8];
          bf16x8 bk1 = *(const bf16x8*)&Ks2[0][nn*16 + fr][32 + fg*8];
          acc[nn] = __builtin_amdgcn_mfma_f32_16x16x32_bf16(bk0, aqH[0], acc[nn], 0, 0, 0);
          acc[nn] = __builtin_amdgcn_mfma_f32_16x16x32_bf16(bk1, aqH[1], acc[nn], 0, 0, 0);
        }
        const bool diag = (jt == NT - 1);
#pragma unroll
        for (int nn = 0; nn < 4; ++nn) {
          f32x4 pv;
          bf16x4 pb;
#pragma unroll
          for (int r = 0; r < 4; ++r) {
            float e = __expf(acc[nn][r] * 0.125f) * rsH;
            pv[r] = (diag && (nn * 16 + cb + r > thr)) ? 0.f : e;
            pb[r] = (bf16)pv[r];
          }
          *(f32x4*)&awpH[j0 + nn * 16 + cb] = pv;   // plain cached store
          *(bf16x4*)&Ps[wave][fr][nn * 16 + cb] = pb;
        }
        bf16x8 pa0 = *(const bf16x8*)&Ps[wave][fr][fg * 8];
        bf16x8 pa1 = *(const bf16x8*)&Ps[wave][fr][32 + fg * 8];
#pragma unroll
        for (int nn = 0; nn < 4; ++nn) {
          bf16x8 bv0 = *(const bf16x8*)&Vs[nn*16 + fr][fg*8];
          bf16x8 bv1 = *(const bf16x8*)&Vs[nn*16 + fr][32 + fg*8];
          oH[nn] = __builtin_amdgcn_mfma_f32_16x16x32_bf16(pa0, bv0, oH[nn], 0, 0, 0);
          oH[nn] = __builtin_amdgcn_mfma_f32_16x16x32_bf16(pa1, bv1, oH[nn], 0, 0, 0);
        }
      }
      // ---- LO stripe (jt <= qt; block-uniform) ----
      if (jt <= qt) {
        f32x4 acc[4] = {};
#pragma unroll
        for (int nn = 0; nn < 4; ++nn) {
          bf16x8 bk0 = *(const bf16x8*)&Ks2[0][nn*16 + fr][fg*8];
          bf16x8 bk1 = *(const bf16x8*)&Ks2[0][nn*16 + fr][32 + fg*8];
          acc[nn] = __builtin_amdgcn_mfma_f32_16x16x32_bf16(bk0, aqL[0], acc[nn], 0, 0, 0);
          acc[nn] = __builtin_amdgcn_mfma_f32_16x16x32_bf16(bk1, aqL[1], acc[nn], 0, 0, 0);
        }
        const bool diag = (jt == qt);
#pragma unroll
        for (int nn = 0; nn < 4; ++nn) {
          f32x4 pv;
          bf16x4 pb;
#pragma unroll
          for (int r = 0; r < 4; ++r) {
            float e = __expf(acc[nn][r] * 0.125f) * rsL;
            pv[r] = (diag && (nn * 16 + cb + r > thr)) ? 0.f : e;
            pb[r] = (bf16)pv[r];
          }
          *(f32x4*)&awpL[j0 + nn * 16 + cb] = pv;   // plain cached store
          *(bf16x4*)&Ps[wave][fr][nn * 16 + cb] = pb;
        }
        bf16x8 pa0 = *(const bf16x8*)&Ps[wave][fr][fg * 8];
        bf16x8 pa1 = *(const bf16x8*)&Ps[wave][fr][32 + fg * 8];
#pragma unroll
        for (int nn = 0; nn < 4; ++nn) {
          bf16x8 bv0 = *(const bf16x8*)&Vs[nn*16 + fr][fg*8];
          bf16x8 bv1 = *(const bf16x8*)&Vs[nn*16 + fr][32 + fg*8];
          oL[nn] = __builtin_amdgcn_mfma_f32_16x16x32_bf16(pa0, bv0, oL[nn], 0, 0, 0);
          oL[nn] = __builtin_amdgcn_mfma_f32_16x16x32_bf16(pa1, bv1, oL[nn], 0, 0, 0);
        }
      }
    }
  }

  // attn_out (bf16) for both stripes (PV D-layout: row q = rt+r, col d = nn*16+fr)
#pragma unroll
  for (int nn = 0; nn < 4; ++nn)
#pragma unroll
    for (int r = 0; r < 4; ++r) {
      int rowL = qLo + rt + r;
      int rowH = qHi + rt + r;
      attn_out[(size_t)(b * S_ + rowL) * (NH_*HD_) + h * 64 + nn * 16 + fr] = (bf16)oL[nn][r];
      attn_out[(size_t)(b * S_ + rowH) * (NH_*HD_) + h * 64 + nn * 16 + fr] = (bf16)oH[nn][r];
    }
}

// ---------------------------------------------------------------------------
extern "C" void kernel_launch(void* const* d_in, const int* in_sizes, int n_in,
                              void* d_out, int out_size, void* d_ws, size_t ws_size,
                              hipStream_t stream) {
  const float* hs   = (const float*)d_in[0];
  const float* cosp = (const float*)d_in[1];
  const float* sinp = (const float*)d_in[2];
  // d_in[3] = attention_mask (causal; applied analytically)
  const float* Wq = (const float*)d_in[4];
  const float* Wk = (const float*)d_in[5];
  const float* Wv = (const float*)d_in[6];
  const float* Wo = (const float*)d_in[7];

  char* ws = (char*)d_ws;
  bf16* hs_b   = (bf16*)(ws);                   // 16 MB
  bf16* qkv_b  = (bf16*)(ws + (16u << 20));     // 24 MB (TOK x 3072)
  bf16* vT_b   = (bf16*)(ws + (40u << 20));     // 4 MB
  bf16* ao_b   = (bf16*)(ws + (44u << 20));     // 16 MB
  bf16* Wqkv_b = (bf16*)(ws + (60u << 20));     // 12 MB (3072 x 2048)
  bf16* Wo_b   = (bf16*)(ws + (72u << 20));     // 8 MB

  float* outp  = (float*)d_out;
  float* attnw = outp + (size_t)TOK_ * HID_;    // + 8388608

  // all casts in one kernel
  cast_all<<<(4718592 + 255)/256, 256, 0, stream>>>(hs, Wq, Wk, Wv, Wo,
                                                    hs_b, Wqkv_b, Wo_b);

  // fused QKV projection + RoPE epilogue: (TOK,2048) @ (3072,2048)^T -> (TOK,3072)
  gemm_bt<false, true><<<dim3(QKVN/128, TOK_/128), 256, 0, stream>>>(
      hs_b, Wqkv_b, qkv_b, TOK_, QKVN, HID_, cosp, sinp);

  // V transpose for PV B-operand contiguity
  transpose_v<<<dim3(S_/64, B_*NKV_), 256, 0, stream>>>(qkv_b + 2560, vT_b);

  // fused attention (stripe-paired; writes attn_weights f32 + attn_out bf16)
  attn_kernel<<<dim3(S_/128, B_*NH_), 256, 0, stream>>>(qkv_b, vT_b, attnw, ao_b);

  // output projection (f32 out)
  gemm_bt<true, false><<<dim3(HID_/128, TOK_/128), 256, 0, stream>>>(
      ao_b, Wo_b, outp, TOK_, HID_, HID_, nullptr, nullptr);
}

// Round 13
// 426.804 us; speedup vs baseline: 1.1696x; 1.0536x over previous
//
#include <hip/hip_runtime.h>
#include <hip/hip_bf16.h>

// ---------------------------------------------------------------------------
// SmallthinkerAttention: hs->QKV proj -> RoPE -> causal attn (writes P) -> out proj
// B=2 S=2048 HID=2048 NH=32 NKV=8 HD=64
// d_out = [out (2*2048*2048 f32), attn_weights (2*32*2048*2048 f32)]
// R13: single-variable revert of R11/R12's RoPE-in-GEMM-epilogue (isolated as
//      -16us: scattered cos/sin scalar loads + doubled scalar stores in the hot
//      GEMM). Standalone rope_fused kernel restored. cast_all kept (neutral+).
//      Attn = R9 structure (cached f32x4 P stores, NT zero-fill, lgkm barriers).
// ---------------------------------------------------------------------------

typedef __bf16 bf16;
typedef bf16 bf16x8 __attribute__((ext_vector_type(8)));
typedef bf16 bf16x4 __attribute__((ext_vector_type(4)));
typedef float f32x4 __attribute__((ext_vector_type(4)));

#define B_   2
#define S_   2048
#define HID_ 2048
#define NH_  32
#define NKV_ 8
#define HD_  64
#define TOK_ (B_*S_)          // 4096
#define QKVN 3072             // fused QKV output cols: 2048 q | 512 k | 512 v

// barrier WITHOUT the implicit vmcnt(0) drain
#define BAR_LGKM() do { asm volatile("s_waitcnt lgkmcnt(0)" ::: "memory"); \
                        __builtin_amdgcn_s_barrier(); } while (0)

// async global->LDS, 16B per lane, LDS dest = wave-uniform base + lane*16
__device__ __forceinline__ void gl_lds16(const bf16* g, bf16* l) {
  __builtin_amdgcn_global_load_lds(
      (const __attribute__((address_space(1))) unsigned int*)(g),
      (__attribute__((address_space(3))) unsigned int*)(l), 16, 0, 0);
}

// ---------------- fused cast: hs | Wq | Wk | Wv | Wo -> bf16 ----------------
// x4 units: hs 2097152 | Wq 1048576 | Wk 262144 | Wv 262144 | Wo 1048576
__global__ __launch_bounds__(256) void cast_all(const float* __restrict__ hs,
                                                const float* __restrict__ wq,
                                                const float* __restrict__ wk,
                                                const float* __restrict__ wv,
                                                const float* __restrict__ wo,
                                                bf16* __restrict__ hs_b,
                                                bf16* __restrict__ wqkv_b,
                                                bf16* __restrict__ wo_b) {
  int i = blockIdx.x * 256 + threadIdx.x;      // 0 .. 4718591
  const float* src; bf16* dstb; int off;
  if (i < 2097152)      { src = hs; dstb = hs_b;                       off = i; }
  else if (i < 3145728) { src = wq; dstb = wqkv_b;                     off = i - 2097152; }
  else if (i < 3407872) { src = wk; dstb = wqkv_b + (size_t)4194304;   off = i - 3145728; }
  else if (i < 3670016) { src = wv; dstb = wqkv_b + (size_t)5242880;   off = i - 3407872; }
  else                  { src = wo; dstb = wo_b;                       off = i - 3670016; }
  f32x4 v = ((const f32x4*)src)[off];
  bf16x4 o;
  o[0] = (bf16)v[0]; o[1] = (bf16)v[1]; o[2] = (bf16)v[2]; o[3] = (bf16)v[3];
  ((bf16x4*)dstb)[off] = o;
}

// ---------------- GEMM: C[M,N] = A[M,K] @ B[N,K]^T  (m97 128^2 + T1) ----------
template<bool OUT_F32>
__global__ __launch_bounds__(256) void gemm_bt(const bf16* __restrict__ A,
                                               const bf16* __restrict__ Bm,
                                               void* __restrict__ Cout,
                                               int M, int N, int K) {
  __shared__ __align__(16) bf16 As[128 * 32];
  __shared__ __align__(16) bf16 Bs[128 * 32];
  const int tid  = threadIdx.x;
  const int wave = tid >> 6, lane = tid & 63;

  // T1 XCD-aware swizzle (nwg % 8 == 0 for all our launches)
  const int nwg = (int)(gridDim.x * gridDim.y);
  const int bid = (int)(blockIdx.y * gridDim.x + blockIdx.x);
  const int swz = (bid & 7) * (nwg >> 3) + (bid >> 3);
  const int bx = swz % (int)gridDim.x, by = swz / (int)gridDim.x;

  const int bm = by * 128, bn = bx * 128;
  const int wm = (wave >> 1) * 64, wn = (wave & 1) * 64;
  const int fr = lane & 15, fg = lane >> 4;

  const int r0   = wave * 32 + (lane >> 2);
  const int scol = (lane & 3) * 8;
  const bf16* ga0 = A  + (size_t)(bm + r0) * K + scol;
  const bf16* ga1 = ga0 + (size_t)16 * K;
  const bf16* gb0 = Bm + (size_t)(bn + r0) * K + scol;
  const bf16* gb1 = gb0 + (size_t)16 * K;
  bf16* lA0 = As + (wave * 32) * 32;
  bf16* lA1 = lA0 + 16 * 32;
  bf16* lB0 = Bs + (wave * 32) * 32;
  bf16* lB1 = lB0 + 16 * 32;

  f32x4 acc[4][4] = {};

  for (int k0 = 0; k0 < K; k0 += 32) {
    gl_lds16(ga0 + k0, lA0);
    gl_lds16(ga1 + k0, lA1);
    gl_lds16(gb0 + k0, lB0);
    gl_lds16(gb1 + k0, lB1);
    __syncthreads();
    bf16x8 af[4], bfv[4];
#pragma unroll
    for (int i = 0; i < 4; ++i) {
      af[i]  = *(const bf16x8*)&As[(wm + i * 16 + fr) * 32 + fg * 8];
      bfv[i] = *(const bf16x8*)&Bs[(wn + i * 16 + fr) * 32 + fg * 8];
    }
#pragma unroll
    for (int i = 0; i < 4; ++i)
#pragma unroll
      for (int j = 0; j < 4; ++j)
        acc[i][j] = __builtin_amdgcn_mfma_f32_16x16x32_bf16(af[i], bfv[j], acc[i][j], 0, 0, 0);
    __syncthreads();
  }

#pragma unroll
  for (int i = 0; i < 4; ++i)
#pragma unroll
    for (int j = 0; j < 4; ++j)
#pragma unroll
      for (int r = 0; r < 4; ++r) {
        int row = bm + wm + i * 16 + fg * 4 + r;
        int col = bn + wn + j * 16 + fr;
        float v = acc[i][j][r];
        if (OUT_F32) ((float*)Cout)[(size_t)row * N + col] = v;
        else         ((bf16*)Cout)[(size_t)row * N + col] = (bf16)v;
      }
}

// ---------------- RoPE: one block per token, q (32 heads) + k (8 heads) ------
__global__ __launch_bounds__(256) void rope_fused(bf16* __restrict__ qkv,
                                                  const float* __restrict__ cosp,
                                                  const float* __restrict__ sinp) {
  const int t = blockIdx.x;                    // 0..TOK-1
  const int tid = threadIdx.x;
  const int d = tid & 31, g = tid >> 5;        // g 0..7
  const float c = cosp[t * 64 + d];
  const float s = sinp[t * 64 + d];
  bf16* row = qkv + (size_t)t * QKVN;
#pragma unroll
  for (int i = 0; i < 4; ++i) {
    bf16* p = row + (g + i * 8) * 64 + d;      // q heads
    float x1 = (float)p[0], x2 = (float)p[32];
    p[0]  = (bf16)(x1 * c - x2 * s);
    p[32] = (bf16)(x2 * c + x1 * s);
  }
  bf16* p = row + 2048 + g * 64 + d;           // k head
  float x1 = (float)p[0], x2 = (float)p[32];
  p[0]  = (bf16)(x1 * c - x2 * s);
  p[32] = (bf16)(x2 * c + x1 * s);
}

// ---------------- transpose V: qkv v-cols -> vT[(b*8+kv)][64][2048] ----------
__global__ __launch_bounds__(256) void transpose_v(const bf16* __restrict__ v,  // qkv + 2560
                                                   bf16* __restrict__ vT) {
  __shared__ __align__(16) bf16 t[64][72];
  const int bkv = blockIdx.y;
  const int b = bkv >> 3, kv = bkv & 7;
  const int s0 = blockIdx.x * 64;
  const int tid = threadIdx.x;
  const int r = tid >> 3, c = (tid & 7) * 8;
#pragma unroll
  for (int p = 0; p < 2; ++p) {
    int rr = r + p * 32;
    *(bf16x8*)&t[rr][c] = *(const bf16x8*)&v[(size_t)(b * S_ + s0 + rr) * QKVN + kv * 64 + c];
  }
  __syncthreads();
#pragma unroll
  for (int p = 0; p < 2; ++p) {
    int d = r + p * 32;
    bf16x8 o;
#pragma unroll
    for (int j = 0; j < 8; ++j) o[j] = t[c + j][d];
    *(bf16x8*)&vT[((size_t)bkv * 64 + d) * S_ + s0 + c] = o;
  }
}

// ---------------- fused causal attention (stripe-paired, 4 waves) ----------------
// R9 structure: swapped QK^T, raw lgkm barriers, zero-fill first (NT),
// pass1 K-dbuf, pass2 cached f32x4 P stores + PV accumulate.
__global__ __launch_bounds__(256, 4) void attn_kernel(const bf16* __restrict__ qkv, // (TOK, 3072)
                                                      const bf16* __restrict__ vT,  // (16,64,2048)
                                                      float* __restrict__ attnw,    // (64, S, S)
                                                      bf16* __restrict__ attn_out)  // (TOK, 2048)
{
  __shared__ __align__(16) bf16 Ks2[2][64][72];
  __shared__ __align__(16) bf16 Vs[64][72];
  __shared__ __align__(16) bf16 Ps[4][16][72];

  const int tid  = threadIdx.x;
  const int wave = tid >> 6, lane = tid & 63;
  const int qt = blockIdx.x;                   // 0..15
  const int bh = blockIdx.y;                   // 0..63
  const int b = bh >> 5, h = bh & 31, kv = h >> 2;
  const int qLo = qt * 64;                     // LO stripe base row
  const int qHi = (31 - qt) * 64;              // HI stripe base row
  const int NT  = 32 - qt;                     // K/V tiles staged (HI needs all)
  const int fr = lane & 15, fg = lane >> 4;
  const int rw = wave * 16;                    // wave's row base within stripe
  const int rt = rw + fg * 4;                  // attn_out row group
  const int thr = rw + fr;                     // lane's q-row within stripe (diag threshold)

  const int lr = tid >> 2;                     // 0..63
  const int lc = (tid & 3) * 16;               // 0,16,32,48
  const bf16* kbase = qkv + (size_t)(b * S_) * QKVN + 2048 + kv * 64;
  const bf16* vbase = vT + (size_t)(b * NKV_ + kv) * 64 * S_;
  const bf16* kst = kbase + (size_t)lr * QKVN + lc;   // + jt*64*QKVN
  const bf16* vst = vbase + (size_t)lr * S_ + lc;     // + jt*64

  // tile-0 K loads FIRST (in-order vmcnt: retire before the zero-fill stores)
  bf16x8 kr0 = *(const bf16x8*)(kst);
  bf16x8 kr1 = *(const bf16x8*)(kst + 8);

  // Q fragments for both stripes (K=64 -> 2 chunks of 32); used as MFMA B-operand.
  bf16x8 aqL[2], aqH[2];
  {
    const bf16* qp = qkv + (size_t)(b * S_ + qLo + rw + fr) * QKVN + h * 64 + fg * 8;
    aqL[0] = *(const bf16x8*)qp;  aqL[1] = *(const bf16x8*)(qp + 32);
    qp = qkv + (size_t)(b * S_ + qHi + rw + fr) * QKVN + h * 64 + fg * 8;
    aqH[0] = *(const bf16x8*)qp;  aqH[1] = *(const bf16x8*)(qp + 32);
  }

  // ---------- zero-fill masked regions (background NT stores) ----------
  {
    f32x4 z4 = {0.f, 0.f, 0.f, 0.f};
    const int zLo = (qt + 1) * 64;              // LO rows: cols [zLo, S)
    for (int rr = 0; rr < 16; ++rr) {
      size_t base = ((size_t)bh * S_ + qLo + rw + rr) * S_;
      for (int c = zLo + lane * 4; c < S_; c += 256)
        __builtin_nontemporal_store(z4, (f32x4*)&attnw[base + c]);
    }
    const int zHi = NT * 64;                    // HI rows: cols [zHi, S)
    for (int rr = 0; rr < 16; ++rr) {
      size_t base = ((size_t)bh * S_ + qHi + rw + rr) * S_;
      for (int c = zHi + lane * 4; c < S_; c += 256)
        __builtin_nontemporal_store(z4, (f32x4*)&attnw[base + c]);
    }
  }

  // ---------- pass 1: rowsums of exp(logit), K double-buffered ----------
  float rsL = 0.f, rsH = 0.f;                  // scalar: lane owns q-row fr
  {
    *(bf16x8*)&Ks2[0][lr][lc]     = kr0;
    *(bf16x8*)&Ks2[0][lr][lc + 8] = kr1;
    BAR_LGKM();
    for (int jt = 0; jt < NT; ++jt) {
      const int cur = jt & 1;
      if (jt + 1 < NT) {                        // prefetch next tile to regs
        const bf16* p = kst + (size_t)(jt + 1) * 64 * QKVN;
        kr0 = *(const bf16x8*)(p);
        kr1 = *(const bf16x8*)(p + 8);
      }
      // HI stripe (always active)
      {
        f32x4 acc[4] = {};
#pragma unroll
        for (int nn = 0; nn < 4; ++nn) {
          bf16x8 bk0 = *(const bf16x8*)&Ks2[cur][nn*16 + fr][fg*8];
          bf16x8 bk1 = *(const bf16x8*)&Ks2[cur][nn*16 + fr][32 + fg*8];
          acc[nn] = __builtin_amdgcn_mfma_f32_16x16x32_bf16(bk0, aqH[0], acc[nn], 0, 0, 0);
          acc[nn] = __builtin_amdgcn_mfma_f32_16x16x32_bf16(bk1, aqH[1], acc[nn], 0, 0, 0);
        }
        if (jt < NT - 1) {                      // fully unmasked
#pragma unroll
          for (int nn = 0; nn < 4; ++nn)
#pragma unroll
            for (int r = 0; r < 4; ++r) rsH += __expf(acc[nn][r] * 0.125f);
        } else {                                // HI diagonal tile: k <= q
#pragma unroll
          for (int nn = 0; nn < 4; ++nn)
#pragma unroll
            for (int r = 0; r < 4; ++r)
              if (nn * 16 + fg * 4 + r <= thr) rsH += __expf(acc[nn][r] * 0.125f);
        }
      }
      // LO stripe (active for jt <= qt; block-uniform)
      if (jt <= qt) {
        f32x4 acc[4] = {};
#pragma unroll
        for (int nn = 0; nn < 4; ++nn) {
          bf16x8 bk0 = *(const bf16x8*)&Ks2[cur][nn*16 + fr][fg*8];
          bf16x8 bk1 = *(const bf16x8*)&Ks2[cur][nn*16 + fr][32 + fg*8];
          acc[nn] = __builtin_amdgcn_mfma_f32_16x16x32_bf16(bk0, aqL[0], acc[nn], 0, 0, 0);
          acc[nn] = __builtin_amdgcn_mfma_f32_16x16x32_bf16(bk1, aqL[1], acc[nn], 0, 0, 0);
        }
        if (jt < qt) {
#pragma unroll
          for (int nn = 0; nn < 4; ++nn)
#pragma unroll
            for (int r = 0; r < 4; ++r) rsL += __expf(acc[nn][r] * 0.125f);
        } else {                                // LO diagonal tile
#pragma unroll
          for (int nn = 0; nn < 4; ++nn)
#pragma unroll
            for (int r = 0; r < 4; ++r)
              if (nn * 16 + fg * 4 + r <= thr) rsL += __expf(acc[nn][r] * 0.125f);
        }
      }
      if (jt + 1 < NT) {                        // stage next tile, ONE barrier
        *(bf16x8*)&Ks2[cur ^ 1][lr][lc]     = kr0;
        *(bf16x8*)&Ks2[cur ^ 1][lr][lc + 8] = kr1;
        BAR_LGKM();
      }
    }
  }
  // reduce across the 4 fg lane-groups (k-partitions), then invert
  {
    float v = rsL;
    v += __shfl_xor(v, 16); v += __shfl_xor(v, 32);
    rsL = 1.0f / v;
    v = rsH;
    v += __shfl_xor(v, 16); v += __shfl_xor(v, 32);
    rsH = 1.0f / v;
  }

  // ---------- pass 2: recompute (swapped), write P cached f32x4, accumulate O ----------
  f32x4 oL[4] = {}, oH[4] = {};
  {
    float* awpL = attnw + ((size_t)bh * S_ + qLo + rw + fr) * S_;   // lane's LO row
    float* awpH = attnw + ((size_t)bh * S_ + qHi + rw + fr) * S_;   // lane's HI row
    const int cb = fg * 4;                      // lane's 4-col base within 16-window
    kr0 = *(const bf16x8*)(kst);               // prefetch tile 0
    kr1 = *(const bf16x8*)(kst + 8);
    bf16x8 vr0 = *(const bf16x8*)(vst);
    bf16x8 vr1 = *(const bf16x8*)(vst + 8);
    for (int jt = 0; jt < NT; ++jt) {
      const int j0 = jt * 64;
      BAR_LGKM();                               // all waves done reading prev tile
      *(bf16x8*)&Ks2[0][lr][lc]     = kr0;
      *(bf16x8*)&Ks2[0][lr][lc + 8] = kr1;
      *(bf16x8*)&Vs[lr][lc]     = vr0;
      *(bf16x8*)&Vs[lr][lc + 8] = vr1;
      BAR_LGKM();                               // stage visible
      if (jt + 1 < NT) {                        // loads issued BEFORE this tile's stores
        const bf16* p = kst + (size_t)(jt + 1) * 64 * QKVN;
        kr0 = *(const bf16x8*)(p);
        kr1 = *(const bf16x8*)(p + 8);
        p = vst + (size_t)(jt + 1) * 64;
        vr0 = *(const bf16x8*)(p);
        vr1 = *(const bf16x8*)(p + 8);
      }
      // ---- HI stripe (always) ----
      {
        f32x4 acc[4] = {};
#pragma unroll
        for (int nn = 0; nn < 4; ++nn) {
          bf16x8 bk0 = *(const bf16x8*)&Ks2[0][nn*16 + fr][fg*8];
          bf16x8 bk1 = *(const bf16x8*)&Ks2[0][nn*16 + fr][32 + fg*8];
          acc[nn] = __builtin_amdgcn_mfma_f32_16x16x32_bf16(bk0, aqH[0], acc[nn], 0, 0, 0);
          acc[nn] = __builtin_amdgcn_mfma_f32_16x16x32_bf16(bk1, aqH[1], acc[nn], 0, 0, 0);
        }
        const bool diag = (jt == NT - 1);
#pragma unroll
        for (int nn = 0; nn < 4; ++nn) {
          f32x4 pv;
          bf16x4 pb;
#pragma unroll
          for (int r = 0; r < 4; ++r) {
            float e = __expf(acc[nn][r] * 0.125f) * rsH;
            pv[r] = (diag && (nn * 16 + cb + r > thr)) ? 0.f : e;
            pb[r] = (bf16)pv[r];
          }
          *(f32x4*)&awpH[j0 + nn * 16 + cb] = pv;   // plain cached store
          *(bf16x4*)&Ps[wave][fr][nn * 16 + cb] = pb;
        }
        bf16x8 pa0 = *(const bf16x8*)&Ps[wave][fr][fg * 8];
        bf16x8 pa1 = *(const bf16x8*)&Ps[wave][fr][32 + fg * 8];
#pragma unroll
        for (int nn = 0; nn < 4; ++nn) {
          bf16x8 bv0 = *(const bf16x8*)&Vs[nn*16 + fr][fg*8];
          bf16x8 bv1 = *(const bf16x8*)&Vs[nn*16 + fr][32 + fg*8];
          oH[nn] = __builtin_amdgcn_mfma_f32_16x16x32_bf16(pa0, bv0, oH[nn], 0, 0, 0);
          oH[nn] = __builtin_amdgcn_mfma_f32_16x16x32_bf16(pa1, bv1, oH[nn], 0, 0, 0);
        }
      }
      // ---- LO stripe (jt <= qt; block-uniform) ----
      if (jt <= qt) {
        f32x4 acc[4] = {};
#pragma unroll
        for (int nn = 0; nn < 4; ++nn) {
          bf16x8 bk0 = *(const bf16x8*)&Ks2[0][nn*16 + fr][fg*8];
          bf16x8 bk1 = *(const bf16x8*)&Ks2[0][nn*16 + fr][32 + fg*8];
          acc[nn] = __builtin_amdgcn_mfma_f32_16x16x32_bf16(bk0, aqL[0], acc[nn], 0, 0, 0);
          acc[nn] = __builtin_amdgcn_mfma_f32_16x16x32_bf16(bk1, aqL[1], acc[nn], 0, 0, 0);
        }
        const bool diag = (jt == qt);
#pragma unroll
        for (int nn = 0; nn < 4; ++nn) {
          f32x4 pv;
          bf16x4 pb;
#pragma unroll
          for (int r = 0; r < 4; ++r) {
            float e = __expf(acc[nn][r] * 0.125f) * rsL;
            pv[r] = (diag && (nn * 16 + cb + r > thr)) ? 0.f : e;
            pb[r] = (bf16)pv[r];
          }
          *(f32x4*)&awpL[j0 + nn * 16 + cb] = pv;   // plain cached store
          *(bf16x4*)&Ps[wave][fr][nn * 16 + cb] = pb;
        }
        bf16x8 pa0 = *(const bf16x8*)&Ps[wave][fr][fg * 8];
        bf16x8 pa1 = *(const bf16x8*)&Ps[wave][fr][32 + fg * 8];
#pragma unroll
        for (int nn = 0; nn < 4; ++nn) {
          bf16x8 bv0 = *(const bf16x8*)&Vs[nn*16 + fr][fg*8];
          bf16x8 bv1 = *(const bf16x8*)&Vs[nn*16 + fr][32 + fg*8];
          oL[nn] = __builtin_amdgcn_mfma_f32_16x16x32_bf16(pa0, bv0, oL[nn], 0, 0, 0);
          oL[nn] = __builtin_amdgcn_mfma_f32_16x16x32_bf16(pa1, bv1, oL[nn], 0, 0, 0);
        }
      }
    }
  }

  // attn_out (bf16) for both stripes (PV D-layout: row q = rt+r, col d = nn*16+fr)
#pragma unroll
  for (int nn = 0; nn < 4; ++nn)
#pragma unroll
    for (int r = 0; r < 4; ++r) {
      int rowL = qLo + rt + r;
      int rowH = qHi + rt + r;
      attn_out[(size_t)(b * S_ + rowL) * (NH_*HD_) + h * 64 + nn * 16 + fr] = (bf16)oL[nn][r];
      attn_out[(size_t)(b * S_ + rowH) * (NH_*HD_) + h * 64 + nn * 16 + fr] = (bf16)oH[nn][r];
    }
}

// ---------------------------------------------------------------------------
extern "C" void kernel_launch(void* const* d_in, const int* in_sizes, int n_in,
                              void* d_out, int out_size, void* d_ws, size_t ws_size,
                              hipStream_t stream) {
  const float* hs   = (const float*)d_in[0];
  const float* cosp = (const float*)d_in[1];
  const float* sinp = (const float*)d_in[2];
  // d_in[3] = attention_mask (causal; applied analytically)
  const float* Wq = (const float*)d_in[4];
  const float* Wk = (const float*)d_in[5];
  const float* Wv = (const float*)d_in[6];
  const float* Wo = (const float*)d_in[7];

  char* ws = (char*)d_ws;
  bf16* hs_b   = (bf16*)(ws);                   // 16 MB
  bf16* qkv_b  = (bf16*)(ws + (16u << 20));     // 24 MB (TOK x 3072)
  bf16* vT_b   = (bf16*)(ws + (40u << 20));     // 4 MB
  bf16* ao_b   = (bf16*)(ws + (44u << 20));     // 16 MB
  bf16* Wqkv_b = (bf16*)(ws + (60u << 20));     // 12 MB (3072 x 2048)
  bf16* Wo_b   = (bf16*)(ws + (72u << 20));     // 8 MB

  float* outp  = (float*)d_out;
  float* attnw = outp + (size_t)TOK_ * HID_;    // + 8388608

  // all casts in one kernel
  cast_all<<<(4718592 + 255)/256, 256, 0, stream>>>(hs, Wq, Wk, Wv, Wo,
                                                    hs_b, Wqkv_b, Wo_b);

  // fused QKV projection: (TOK,2048) @ (3072,2048)^T -> (TOK,3072)
  gemm_bt<false><<<dim3(QKVN/128, TOK_/128), 256, 0, stream>>>(
      hs_b, Wqkv_b, qkv_b, TOK_, QKVN, HID_);

  // RoPE (in place, one block per token)
  rope_fused<<<TOK_, 256, 0, stream>>>(qkv_b, cosp, sinp);

  // V transpose for PV B-operand contiguity
  transpose_v<<<dim3(S_/64, B_*NKV_), 256, 0, stream>>>(qkv_b + 2560, vT_b);

  // fused attention (stripe-paired; writes attn_weights f32 + attn_out bf16)
  attn_kernel<<<dim3(S_/128, B_*NH_), 256, 0, stream>>>(qkv_b, vT_b, attnw, ao_b);

  // output projection (f32 out)
  gemm_bt<true><<<dim3(HID_/128, TOK_/128), 256, 0, stream>>>(
      ao_b, Wo_b, outp, TOK_, HID_, HID_);
}